// Round 1
// baseline (139.442 us; speedup 1.0000x reference)
//
#include <hip/hip_runtime.h>

// Quantized 3x3 conv, stride 1, pad 1:
//   x: [32,64,112,112] fp32  -> q uint4-range [0,15]
//   w: [128,64,3,3]    fp32  -> q int4-range  [-8,7]
//   out: [32,128,112,112] fp32 (integer-exact)
//
// Pipeline:
//   k0: zero-fill padded int8 NHWC activation buffer in d_ws
//   k1: quantize+reorder weights -> wq[cout][kh][kw][cin] int8
//   k2: quantize+transpose x NCHW fp32 -> xq[n][h+1][w+1][c] int8 (padded 114x114)
//   k3: implicit-GEMM conv with v_mfma_i32_16x16x64_i8
//       D[cout][spatial] = W[cout][576] * X[576][spatial]

#define NIMG 32
#define CIN  64
#define HH   112
#define WW   112
#define COUT 128
#define HP   114
#define WP   114
#define KTOT 576            // 64*3*3
#define LDSW 592            // 576 + 16B pad -> 2-way bank aliasing (free)

#define XQ_BYTES (NIMG * HP * WP * CIN)          // 26,615,808
#define WQ_BYTES (COUT * KTOT)                   // 73,728

typedef __attribute__((ext_vector_type(4))) int int32x4;

__global__ void k_zero_fill(int32x4* __restrict__ p, int n16) {
    int i = blockIdx.x * blockDim.x + threadIdx.x;
    if (i < n16) p[i] = (int32x4)(0);
}

__global__ void k_quant_w(const float* __restrict__ w, char* __restrict__ wq) {
    int idx = blockIdx.x * 256 + threadIdx.x;       // 73728 total
    int o  = idx / KTOT;
    int r  = idx % KTOT;
    int kh = r / 192;
    int kw = (r / 64) % 3;
    int c  = r % 64;
    float v = w[((o * CIN + c) * 3 + kh) * 3 + kw];
    float q = rintf(v);                              // round-nearest-even == jnp.round
    q = fminf(fmaxf(q, -8.0f), 7.0f);
    wq[idx] = (char)(int)q;
}

// One thread per (n,h,w); loops c=0..63, packs into 64 bytes, one 64B store.
__global__ void k_quant_x(const float* __restrict__ x, char* __restrict__ xq) {
    int bid = blockIdx.x;            // n*112 + h
    int n = bid / HH;
    int h = bid % HH;
    int w = threadIdx.x;
    if (w >= WW) return;
    const float* px = x + (((size_t)n * CIN) * HH + h) * WW + w;   // x[n][0][h][w]
    unsigned int buf[16];
#pragma unroll
    for (int cw = 0; cw < 16; ++cw) {
        unsigned int word = 0;
#pragma unroll
        for (int j = 0; j < 4; ++j) {
            int c = cw * 4 + j;
            float v = px[(size_t)c * (HH * WW)];
            float q = rintf(v);
            q = fminf(fmaxf(q, 0.0f), 15.0f);
            word |= ((unsigned int)(int)q) << (j * 8);
        }
        buf[cw] = word;
    }
    char* dst = xq + (((size_t)n * HP + (h + 1)) * WP + (w + 1)) * 64;
    int32x4* d4 = (int32x4*)dst;
#pragma unroll
    for (int i = 0; i < 4; ++i) {
        int32x4 v;
        v.x = (int)buf[i * 4 + 0];
        v.y = (int)buf[i * 4 + 1];
        v.z = (int)buf[i * 4 + 2];
        v.w = (int)buf[i * 4 + 3];
        d4[i] = v;
    }
}

// Block: 256 threads (4 waves). Block handles 128 consecutive spatial positions
// (one image: 12544 % 128 == 0) x all 128 cout. Wave: 32 spatial x 128 cout.
__global__ __launch_bounds__(256) void k_conv(const char* __restrict__ xq,
                                              const char* __restrict__ wq,
                                              float* __restrict__ out) {
    __shared__ char wlds[COUT * LDSW];   // 75,776 B

    int tid = threadIdx.x;
    // Stage all weights into LDS: 4608 chunks of 16B (= 18 iters * 256 threads)
    for (int i = tid; i < COUT * (KTOT / 16); i += 256) {
        int row = i / (KTOT / 16);
        int ch  = i % (KTOT / 16);
        int32x4 v = *(const int32x4*)(wq + row * KTOT + ch * 16);
        *(int32x4*)(&wlds[row * LDSW + ch * 16]) = v;
    }
    __syncthreads();

    int wave = tid >> 6;
    int lane = tid & 63;
    int l15  = lane & 15;
    int lk   = lane >> 4;                 // k-chunk 0..3 (16 bytes each)

    int sbase = blockIdx.x * 128 + wave * 32;
    int n  = sbase / (HH * WW);
    int s0 = sbase - n * (HH * WW);       // whole block inside one image

    const char* xbase = xq + (size_t)n * (HP * WP * 64);

    int saddr[2];
#pragma unroll
    for (int tS = 0; tS < 2; ++tS) {
        int sl = s0 + tS * 16 + l15;
        int hh = sl / WW;
        int ww = sl - hh * WW;
        // padded coords: input row = hh + kh, col = ww + kw (kh,kw in 0..2)
        saddr[tS] = (hh * WP + ww) * 64 + lk * 16;
    }

    int32x4 acc[8][2];
#pragma unroll
    for (int i = 0; i < 8; ++i)
#pragma unroll
        for (int j = 0; j < 2; ++j) acc[i][j] = (int32x4)(0);

    int lds_base = l15 * LDSW + lk * 16;

#pragma unroll
    for (int ks = 0; ks < 9; ++ks) {
        int kh = ks / 3, kw = ks % 3;
        int koff = (kh * WP + kw) * 64;
        int32x4 bfrag[2];
#pragma unroll
        for (int tS = 0; tS < 2; ++tS)
            bfrag[tS] = *(const int32x4*)(xbase + saddr[tS] + koff);
#pragma unroll
        for (int tO = 0; tO < 8; ++tO) {
            int32x4 afrag = *(const int32x4*)(&wlds[tO * 16 * LDSW + lds_base + ks * 64]);
            acc[tO][0] = __builtin_amdgcn_mfma_i32_16x16x64_i8(afrag, bfrag[0], acc[tO][0], 0, 0, 0);
            acc[tO][1] = __builtin_amdgcn_mfma_i32_16x16x64_i8(afrag, bfrag[1], acc[tO][1], 0, 0, 0);
        }
    }

    // Epilogue: C/D layout col = lane&15 (spatial), row = (lane>>4)*4 + r (cout)
    float* obase = out + (size_t)n * (COUT * HH * WW);
#pragma unroll
    for (int tO = 0; tO < 8; ++tO) {
#pragma unroll
        for (int tS = 0; tS < 2; ++tS) {
            int sl = s0 + tS * 16 + l15;
#pragma unroll
            for (int r = 0; r < 4; ++r) {
                int co = tO * 16 + lk * 4 + r;
                obase[(size_t)co * (HH * WW) + sl] = (float)acc[tO][tS][r];
            }
        }
    }
}

extern "C" void kernel_launch(void* const* d_in, const int* in_sizes, int n_in,
                              void* d_out, int out_size, void* d_ws, size_t ws_size,
                              hipStream_t stream) {
    const float* x = (const float*)d_in[0];
    const float* w = (const float*)d_in[1];
    float* out = (float*)d_out;

    char* xq = (char*)d_ws;
    char* wq = xq + XQ_BYTES;

    // k0: zero padded activation buffer (borders must be 0)
    int n16 = XQ_BYTES / 16;                            // 1,663,488
    hipLaunchKernelGGL(k_zero_fill, dim3((n16 + 255) / 256), dim3(256), 0, stream,
                       (int32x4*)xq, n16);
    // k1: weights
    hipLaunchKernelGGL(k_quant_w, dim3(WQ_BYTES / 256), dim3(256), 0, stream, w, wq);
    // k2: activations
    hipLaunchKernelGGL(k_quant_x, dim3(NIMG * HH), dim3(128), 0, stream, x, xq);
    // k3: conv
    hipLaunchKernelGGL(k_conv, dim3((NIMG * HH * WW) / 128), dim3(256), 0, stream,
                       xq, wq, out);
}

// Round 2
// 113.522 us; speedup vs baseline: 1.2283x; 1.2283x over previous
//
#include <hip/hip_runtime.h>

// Quantized 3x3 conv, stride 1, pad 1:
//   x: [32,64,112,112] fp32  -> q uint4-range [0,15]
//   w: [128,64,3,3]    fp32  -> q int4-range  [-8,7]
//   out: [32,128,112,112] fp32 (integer-exact)
//
// Pipeline:
//   k1: quantize+reorder weights -> wq[cout][kh][kw][cin] int8
//   k2: quantize+transpose x NCHW fp32 -> xq[n][hp][wp][c] int8 (padded 114x114,
//       borders zeroed here -- no separate fill kernel)
//   k3: implicit-GEMM conv with v_mfma_i32_16x16x64_i8
//       block = 256 spatial x 64 cout; wave = 64 spatial x 64 cout (4x4 tiles)
//       A = activations (global, L2-hot), B = weights (LDS), D row = spatial
//       -> float4 epilogue stores

#define NIMG 32
#define CIN  64
#define HH   112
#define WW   112
#define COUT 128
#define CHALF 64
#define HP   114
#define WP   114
#define KTOT 576            // 64*3*3
#define LDSW 592            // 576 + 16B pad -> 2-way bank aliasing (free)

#define XQ_BYTES (NIMG * HP * WP * CIN)          // 26,615,808
#define WQ_BYTES (COUT * KTOT)                   // 73,728

typedef __attribute__((ext_vector_type(4))) int int32x4;

__global__ void k_quant_w(const float* __restrict__ w, char* __restrict__ wq) {
    int idx = blockIdx.x * 256 + threadIdx.x;       // 73728 total
    int o  = idx / KTOT;
    int r  = idx % KTOT;
    int kh = r / 192;
    int kw = (r / 64) % 3;
    int c  = r % 64;
    float v = w[((o * CIN + c) * 3 + kh) * 3 + kw];
    float q = rintf(v);                              // round-nearest-even == jnp.round
    q = fminf(fmaxf(q, -8.0f), 7.0f);
    wq[idx] = (char)(int)q;
}

// One thread per padded (n,hp,wp). Interior: quantize 64 channels, one 64B store.
// Border: store 64B of zeros.
__global__ void k_quant_x(const float* __restrict__ x, char* __restrict__ xq) {
    int bid = blockIdx.x;            // n*114 + hp
    int n  = bid / HP;
    int hp = bid % HP;
    int wp = threadIdx.x;
    if (wp >= WP) return;
    char* dst = xq + (((size_t)n * HP + hp) * WP + wp) * 64;
    int32x4* d4 = (int32x4*)dst;
    if (hp == 0 || hp == HP - 1 || wp == 0 || wp == WP - 1) {
#pragma unroll
        for (int i = 0; i < 4; ++i) d4[i] = (int32x4)(0);
        return;
    }
    int h = hp - 1, w = wp - 1;
    const float* px = x + (((size_t)n * CIN) * HH + h) * WW + w;   // x[n][0][h][w]
    unsigned int buf[16];
#pragma unroll
    for (int cw = 0; cw < 16; ++cw) {
        unsigned int word = 0;
#pragma unroll
        for (int j = 0; j < 4; ++j) {
            int c = cw * 4 + j;
            float v = px[(size_t)c * (HH * WW)];
            float q = rintf(v);
            q = fminf(fmaxf(q, 0.0f), 15.0f);
            word |= ((unsigned int)(int)q) << (j * 8);
        }
        buf[cw] = word;
    }
#pragma unroll
    for (int i = 0; i < 4; ++i) {
        int32x4 v;
        v.x = (int)buf[i * 4 + 0];
        v.y = (int)buf[i * 4 + 1];
        v.z = (int)buf[i * 4 + 2];
        v.w = (int)buf[i * 4 + 3];
        d4[i] = v;
    }
}

// Grid: 1568 spatial-blocks x 2 cout-halves (interleaved for L2 sharing).
// Block: 256 threads / 4 waves; 256 spatial x 64 cout.
// Wave: 64 spatial x 64 cout = 4x4 tiles of 16x16x64-i8 MFMA.
__global__ __launch_bounds__(256, 4) void k_conv(const char* __restrict__ xq,
                                                 const char* __restrict__ wq,
                                                 float* __restrict__ out) {
    __shared__ char wlds[CHALF * LDSW];   // 37,888 B -> 4 blocks/CU

    int tid  = threadIdx.x;
    int bid  = blockIdx.x;
    int half = bid & 1;
    int sblk = bid >> 1;

    // Stage this half's weights: 64 rows x 36 chunks of 16B = 9 iters
    const char* wsrc = wq + half * (CHALF * KTOT);
    for (int i = tid; i < CHALF * (KTOT / 16); i += 256) {
        int row = i / (KTOT / 16);
        int ch  = i % (KTOT / 16);
        *(int32x4*)(&wlds[row * LDSW + ch * 16]) = *(const int32x4*)(wsrc + row * KTOT + ch * 16);
    }
    __syncthreads();

    int wave = tid >> 6;
    int lane = tid & 63;
    int l15  = lane & 15;
    int lk   = lane >> 4;                 // k-chunk 0..3 (16 bytes each)

    int sbase = sblk * 256 + wave * 64;   // 12544 % 256 == 0 -> wave stays in one image
    int n  = sbase / (HH * WW);
    int s0 = sbase - n * (HH * WW);

    const char* xbase = xq + (size_t)n * (HP * WP * 64);

    int saddr[4];
#pragma unroll
    for (int tS = 0; tS < 4; ++tS) {
        int sl = s0 + tS * 16 + l15;
        int hh = sl / WW;
        int ww = sl - hh * WW;
        saddr[tS] = (hh * WP + ww) * 64 + lk * 16;   // padded coords: +kh rows, +kw cols via koff
    }

    int32x4 acc[4][4];   // [tS][tO]
#pragma unroll
    for (int i = 0; i < 4; ++i)
#pragma unroll
        for (int j = 0; j < 4; ++j) acc[i][j] = (int32x4)(0);

#pragma unroll
    for (int ks = 0; ks < 9; ++ks) {
        int kh = ks / 3, kw = ks % 3;
        int koff = (kh * WP + kw) * 64;
        int32x4 af[4];
#pragma unroll
        for (int tS = 0; tS < 4; ++tS)
            af[tS] = *(const int32x4*)(xbase + saddr[tS] + koff);
#pragma unroll
        for (int tO = 0; tO < 4; ++tO) {
            int32x4 bf = *(const int32x4*)(&wlds[(tO * 16 + l15) * LDSW + lk * 16 + ks * 64]);
#pragma unroll
            for (int tS = 0; tS < 4; ++tS)
                acc[tS][tO] = __builtin_amdgcn_mfma_i32_16x16x64_i8(af[tS], bf, acc[tS][tO], 0, 0, 0);
        }
    }

    // Epilogue: D col = lane&15 -> cout, row = lk*4 + r -> spatial (consecutive)
    float* obase = out + (size_t)n * (COUT * HH * WW) + (size_t)half * CHALF * (HH * WW);
#pragma unroll
    for (int tS = 0; tS < 4; ++tS) {
#pragma unroll
        for (int tO = 0; tO < 4; ++tO) {
            int co = tO * 16 + l15;
            int sl = s0 + tS * 16 + lk * 4;
            float4 v;
            v.x = (float)acc[tS][tO][0];
            v.y = (float)acc[tS][tO][1];
            v.z = (float)acc[tS][tO][2];
            v.w = (float)acc[tS][tO][3];
            *(float4*)(&obase[(size_t)co * (HH * WW) + sl]) = v;
        }
    }
}

extern "C" void kernel_launch(void* const* d_in, const int* in_sizes, int n_in,
                              void* d_out, int out_size, void* d_ws, size_t ws_size,
                              hipStream_t stream) {
    const float* x = (const float*)d_in[0];
    const float* w = (const float*)d_in[1];
    float* out = (float*)d_out;

    char* xq = (char*)d_ws;
    char* wq = xq + XQ_BYTES;

    // k1: weights
    hipLaunchKernelGGL(k_quant_w, dim3(WQ_BYTES / 256), dim3(256), 0, stream, w, wq);
    // k2: activations (also writes the zero border)
    hipLaunchKernelGGL(k_quant_x, dim3(NIMG * HP), dim3(128), 0, stream, x, xq);
    // k3: conv
    hipLaunchKernelGGL(k_conv, dim3((NIMG * HH * WW / 256) * 2), dim3(256), 0, stream,
                       xq, wq, out);
}